// Round 1
// baseline (835.731 us; speedup 1.0000x reference)
//
#include <hip/hip_runtime.h>
#include <math.h>

#define EPS 1e-5f

static constexpr int N_ = 128, C_ = 128, T_ = 256, V_ = 21, E_ = 8, M_ = 13;
static constexpr int TV_ = T_ * V_;             // 5376

// ---------------- Kernel A: mean over T ----------------
// grid: N*C blocks, 256 threads. Each block reduces one (n,c) slab of T*V floats.
__global__ __launch_bounds__(256) void mean_kernel(const float* __restrict__ x,
                                                   float* __restrict__ xm) {
    __shared__ float slab[TV_];        // 5376 floats = 21.5 KB
    __shared__ float partial[V_ * 8];  // 168
    const int nc = blockIdx.x;
    const int tid = threadIdx.x;
    const float4* src4 = (const float4*)(x + (size_t)nc * TV_);
    float4* slab4 = (float4*)slab;
    // 5376 floats = 1344 float4
    #pragma unroll
    for (int it = 0; it < 6; ++it) {
        int idx = it * 256 + tid;
        if (idx < TV_ / 4) slab4[idx] = src4[idx];
    }
    __syncthreads();
    if (tid < V_ * 8) {
        int v = tid >> 3, g = tid & 7;
        float s = 0.f;
        #pragma unroll
        for (int tt = 0; tt < 32; ++tt)
            s += slab[(g * 32 + tt) * V_ + v];
        partial[v * 8 + g] = s;
    }
    __syncthreads();
    if (tid < V_) {
        float s = 0.f;
        #pragma unroll
        for (int g = 0; g < 8; ++g) s += partial[tid * 8 + g];
        xm[(size_t)nc * V_ + tid] = s * (1.0f / T_);
    }
}

// ---------------- Kernel B: H_dyn + A = H^T H per sample ----------------
// grid: N blocks, 64 threads (1 wave)
__global__ __launch_bounds__(64) void hyper_kernel(
    const float* __restrict__ xm,                    // (N,C,V)
    const float* __restrict__ dyn_w,                 // (E,C)
    const float* __restrict__ dyn_b,
    const float* __restrict__ dyn_gamma, const float* __restrict__ dyn_beta,
    const float* __restrict__ dyn_mean, const float* __restrict__ dyn_var,
    float* __restrict__ A_out)                       // (N,21,21)
{
    __shared__ float xs[C_ * V_];   // 2688 floats
    __shared__ float Hs[M_ * V_];   // 273 floats
    const int n = blockIdx.x;
    const int l = threadIdx.x;
    const float* src = xm + (size_t)n * C_ * V_;
    for (int idx = l; idx < C_ * V_; idx += 64) xs[idx] = src[idx];
    __syncthreads();
    // h[e,v] = BN(relu-pre) : 8*21 = 168 entries
    for (int idx = l; idx < E_ * V_; idx += 64) {
        int e = idx / V_, v = idx - e * V_;
        float acc = 0.f;
        for (int c = 0; c < C_; ++c) acc = fmaf(xs[c * V_ + v], dyn_w[e * C_ + c], acc);
        acc += dyn_b[e];
        float scale = dyn_gamma[e] * rsqrtf(dyn_var[e] + EPS);
        acc = (acc - dyn_mean[e]) * scale + dyn_beta[e];
        Hs[idx] = fmaxf(acc, 0.f);  // ReLU; softmax applied next phase
    }
    __syncthreads();
    if (l < E_) {
        // softmax over V for dyn row l
        float row[V_];
        float mx = -1e30f;
        #pragma unroll
        for (int v = 0; v < V_; ++v) { row[v] = Hs[l * V_ + v]; mx = fmaxf(mx, row[v]); }
        float s = 0.f;
        #pragma unroll
        for (int v = 0; v < V_; ++v) { row[v] = __expf(row[v] - mx); s += row[v]; }
        float inv = 1.0f / s;
        #pragma unroll
        for (int v = 0; v < V_; ++v) Hs[l * V_ + v] = row[v] * inv;
    } else if (l < M_) {
        // anatomical finger masks: row 8+i covers v in [1+4i, 5+4i)
        int i = l - E_;
        #pragma unroll
        for (int v = 0; v < V_; ++v)
            Hs[l * V_ + v] = (v >= 1 + 4 * i && v < 5 + 4 * i) ? 1.0f : 0.0f;
    }
    __syncthreads();
    // A[u,w] = sum_m H[m,u] H[m,w]  (441 entries)
    for (int idx = l; idx < V_ * V_; idx += 64) {
        int u = idx / V_, w = idx - u * V_;
        float s = 0.f;
        #pragma unroll
        for (int m = 0; m < M_; ++m) s = fmaf(Hs[m * V_ + u], Hs[m * V_ + w], s);
        A_out[(size_t)n * V_ * V_ + idx] = s;
    }
}

// ---------------- Kernel C: GEMM + BN + ReLU + A-transform + residual ----------------
static constexpr int O_TILE = 32;
static constexpr int T_TILE = 12;
static constexpr int S_TILE = T_TILE * V_;   // 252
static constexpr int U_PAD = 24;             // padded row for 16B-aligned, low-conflict LDS reads

__global__ __launch_bounds__(256) void main_kernel(
    const float* __restrict__ x,
    const float* __restrict__ ft_w,    // (C,C) row-major [o][c]
    const float* __restrict__ ft_b,
    const float* __restrict__ ft_gamma, const float* __restrict__ ft_beta,
    const float* __restrict__ ft_mean, const float* __restrict__ ft_var,
    const float* __restrict__ A_g,     // (N,21,21)
    float* __restrict__ out)
{
    __shared__ float xfs[O_TILE * T_TILE * U_PAD];  // 32*288 = 9216 floats = 36 KB
    __shared__ float scale_s[O_TILE], shift_s[O_TILE];

    const int tt = blockIdx.x;   // 0..21
    const int ob = blockIdx.y;   // 0..3
    const int n  = blockIdx.z;   // 0..127
    const int o0 = ob * O_TILE;
    const int t0 = tt * T_TILE;
    const int nt = min(T_TILE, T_ - t0);
    const int tid = threadIdx.x;

    if (tid < O_TILE) {
        int o = o0 + tid;
        float sc = ft_gamma[o] * rsqrtf(ft_var[o] + EPS);
        scale_s[tid] = sc;
        shift_s[tid] = (ft_b[o] - ft_mean[o]) * sc + ft_beta[o];
    }

    const int s_max = nt * V_;                       // valid column count
    const bool valid = tid < s_max;
    const int s_cl = valid ? tid : (s_max - 1);      // clamped for safe loads

    float acc[O_TILE];
    #pragma unroll
    for (int o = 0; o < O_TILE; ++o) acc[o] = 0.f;

    const float* xn = x + (size_t)n * C_ * TV_ + (size_t)t0 * V_;  // x[n, c=0, t0, 0]

    // GEMM over channels: ft_w reads are thread-uniform -> scalar loads (SGPR broadcast)
    #pragma unroll 4
    for (int c = 0; c < C_; ++c) {
        float xv = xn[(size_t)c * TV_ + s_cl];
        #pragma unroll
        for (int o = 0; o < O_TILE; ++o)
            acc[o] = fmaf(ft_w[(size_t)(o0 + o) * C_ + c], xv, acc[o]);
    }

    __syncthreads();   // scale_s/shift_s ready (and xfs free for writing)

    const int t_own = s_cl / V_;
    const int v_own = s_cl - t_own * V_;
    #pragma unroll
    for (int o = 0; o < O_TILE; ++o) {
        float xf = fmaxf(fmaf(acc[o], scale_s[o], shift_s[o]), 0.f);
        if (valid) xfs[(o * T_TILE + t_own) * U_PAD + v_own] = xf;
    }
    __syncthreads();

    // A-transform: out[o,t,v] = sum_u xf[o,t,u] * A[u,v] + x[n,o,t,v]
    float a_col[V_];
    #pragma unroll
    for (int u = 0; u < V_; ++u)
        a_col[u] = A_g[(size_t)n * V_ * V_ + u * V_ + v_own];

    const size_t ro_base = ((size_t)n * C_ + o0) * TV_ + (size_t)(t0 + t_own) * V_ + v_own;
    #pragma unroll
    for (int o = 0; o < O_TILE; ++o) {
        const float* row = &xfs[(o * T_TILE + t_own) * U_PAD];
        float sum = 0.f;
        #pragma unroll
        for (int u = 0; u < V_; ++u) sum = fmaf(row[u], a_col[u], sum);
        if (valid) out[ro_base + (size_t)o * TV_] = sum + x[ro_base + (size_t)o * TV_];
    }
}

extern "C" void kernel_launch(void* const* d_in, const int* in_sizes, int n_in,
                              void* d_out, int out_size, void* d_ws, size_t ws_size,
                              hipStream_t stream) {
    const float* x         = (const float*)d_in[0];
    const float* dyn_w     = (const float*)d_in[1];
    const float* dyn_b     = (const float*)d_in[2];
    const float* dyn_gamma = (const float*)d_in[3];
    const float* dyn_beta  = (const float*)d_in[4];
    const float* dyn_mean  = (const float*)d_in[5];
    const float* dyn_var   = (const float*)d_in[6];
    const float* ft_w      = (const float*)d_in[7];
    const float* ft_b      = (const float*)d_in[8];
    const float* ft_gamma  = (const float*)d_in[9];
    const float* ft_beta   = (const float*)d_in[10];
    const float* ft_mean   = (const float*)d_in[11];
    const float* ft_var    = (const float*)d_in[12];
    float* out = (float*)d_out;

    float* xm  = (float*)d_ws;                               // N*C*V = 1,376,256 B
    float* A_g = (float*)((char*)d_ws + (size_t)N_ * C_ * V_ * 4);  // N*441*4 = 225,792 B

    mean_kernel<<<N_ * C_, 256, 0, stream>>>(x, xm);
    hyper_kernel<<<N_, 64, 0, stream>>>(xm, dyn_w, dyn_b, dyn_gamma, dyn_beta,
                                        dyn_mean, dyn_var, A_g);
    dim3 grid((T_ + T_TILE - 1) / T_TILE, C_ / O_TILE, N_);
    main_kernel<<<grid, 256, 0, stream>>>(x, ft_w, ft_b, ft_gamma, ft_beta,
                                          ft_mean, ft_var, A_g, out);
}

// Round 3
// 416.928 us; speedup vs baseline: 2.0045x; 2.0045x over previous
//
#include <hip/hip_runtime.h>
#include <hip/hip_bf16.h>
#include <math.h>

#define EPS 1e-5f

static constexpr int N_ = 128, C_ = 128, T_ = 256, V_ = 21, E_ = 8, M_ = 13;
static constexpr int TV_ = T_ * V_;   // 5376
static constexpr int NT_ = 8;         // t's per main block
static constexpr int ST_ = NT_ * V_;  // 168 s-columns per block
static constexpr int SP_ = 176;       // padded to 11 MFMA N-frags
static constexpr int XF_PITCH_F = 178; // fp32 xf row pitch (floats); 4*178*4 % 128 = 32 -> 2-way free

typedef short bf16x8 __attribute__((ext_vector_type(8)));
typedef short s16x4  __attribute__((ext_vector_type(4)));
typedef float f32x4  __attribute__((ext_vector_type(4)));

__device__ inline short f2bf(float v) {
    __hip_bfloat16 b = __float2bfloat16(v);
    return *reinterpret_cast<short*>(&b);
}

// ---------------- Kernel P: fold BN + convert W to bf16 ----------------
__global__ __launch_bounds__(256) void prep_kernel(
    const float* __restrict__ ft_w, const float* __restrict__ ft_b,
    const float* __restrict__ ft_gamma, const float* __restrict__ ft_beta,
    const float* __restrict__ ft_mean, const float* __restrict__ ft_var,
    __hip_bfloat16* __restrict__ w_bf, float* __restrict__ sc_g, float* __restrict__ sh_g)
{
    int tid = blockIdx.x * 256 + threadIdx.x;
    if (tid < C_ * C_) w_bf[tid] = __float2bfloat16(ft_w[tid]);
    if (tid < C_) {
        float sc = ft_gamma[tid] * rsqrtf(ft_var[tid] + EPS);
        sc_g[tid] = sc;
        sh_g[tid] = (ft_b[tid] - ft_mean[tid]) * sc + ft_beta[tid];
    }
}

// ---------------- Kernel A: mean over T ----------------
__global__ __launch_bounds__(256) void mean_kernel(const float* __restrict__ x,
                                                   float* __restrict__ xm) {
    __shared__ float slab[TV_];
    __shared__ float partial[V_ * 8];
    const int nc = blockIdx.x;
    const int tid = threadIdx.x;
    const float4* src4 = (const float4*)(x + (size_t)nc * TV_);
    float4* slab4 = (float4*)slab;
    #pragma unroll
    for (int it = 0; it < 6; ++it) {
        int idx = it * 256 + tid;
        if (idx < TV_ / 4) slab4[idx] = src4[idx];
    }
    __syncthreads();
    if (tid < V_ * 8) {
        int v = tid >> 3, g = tid & 7;
        float s = 0.f;
        #pragma unroll
        for (int tt = 0; tt < 32; ++tt) s += slab[(g * 32 + tt) * V_ + v];
        partial[v * 8 + g] = s;
    }
    __syncthreads();
    if (tid < V_) {
        float s = 0.f;
        #pragma unroll
        for (int g = 0; g < 8; ++g) s += partial[tid * 8 + g];
        xm[(size_t)nc * V_ + tid] = s * (1.0f / T_);
    }
}

// ---------------- Kernel B: H_dyn + A = H^T H per sample ----------------
__global__ __launch_bounds__(64) void hyper_kernel(
    const float* __restrict__ xm, const float* __restrict__ dyn_w,
    const float* __restrict__ dyn_b,
    const float* __restrict__ dyn_gamma, const float* __restrict__ dyn_beta,
    const float* __restrict__ dyn_mean, const float* __restrict__ dyn_var,
    float* __restrict__ A_out)
{
    __shared__ float xs[C_ * V_];
    __shared__ float Hs[M_ * V_];
    const int n = blockIdx.x;
    const int l = threadIdx.x;
    const float* src = xm + (size_t)n * C_ * V_;
    for (int idx = l; idx < C_ * V_; idx += 64) xs[idx] = src[idx];
    __syncthreads();
    for (int idx = l; idx < E_ * V_; idx += 64) {
        int e = idx / V_, v = idx - e * V_;
        float acc = 0.f;
        for (int c = 0; c < C_; ++c) acc = fmaf(xs[c * V_ + v], dyn_w[e * C_ + c], acc);
        acc += dyn_b[e];
        float scale = dyn_gamma[e] * rsqrtf(dyn_var[e] + EPS);
        acc = (acc - dyn_mean[e]) * scale + dyn_beta[e];
        Hs[idx] = fmaxf(acc, 0.f);
    }
    __syncthreads();
    if (l < E_) {
        float row[V_];
        float mx = -1e30f;
        #pragma unroll
        for (int v = 0; v < V_; ++v) { row[v] = Hs[l * V_ + v]; mx = fmaxf(mx, row[v]); }
        float s = 0.f;
        #pragma unroll
        for (int v = 0; v < V_; ++v) { row[v] = __expf(row[v] - mx); s += row[v]; }
        float inv = 1.0f / s;
        #pragma unroll
        for (int v = 0; v < V_; ++v) Hs[l * V_ + v] = row[v] * inv;
    } else if (l < M_) {
        int i = l - E_;
        #pragma unroll
        for (int v = 0; v < V_; ++v)
            Hs[l * V_ + v] = (v >= 1 + 4 * i && v < 5 + 4 * i) ? 1.0f : 0.0f;
    }
    __syncthreads();
    for (int idx = l; idx < V_ * V_; idx += 64) {
        int u = idx / V_, w = idx - u * V_;
        float s = 0.f;
        #pragma unroll
        for (int m = 0; m < M_; ++m) s = fmaf(Hs[m * V_ + u], Hs[m * V_ + w], s);
        A_out[(size_t)n * V_ * V_ + idx] = s;
    }
}

// ---------------- Kernel C: MFMA GEMM + BN/ReLU + A-transform + residual ----------------
// grid (32 s-tiles, 128 n), 512 threads = 8 waves. Wave w owns o in [16w, 16w+16).
__global__ __launch_bounds__(512) void main_kernel(
    const float* __restrict__ x, const __hip_bfloat16* __restrict__ w_bf,
    const float* __restrict__ sc_g, const float* __restrict__ sh_g,
    const float* __restrict__ A_g, float* __restrict__ out)
{
    // phase 1: X_t[s][c] bf16 swizzled (176*256 = 45056 B)
    // phase 2: xf fp32, 64 rows x pitch 178 floats (45568 B) per pass
    __shared__ __align__(16) char lds[64 * XF_PITCH_F * 4];
    __shared__ float A_s[V_ * V_];
    __shared__ float sc_s[C_], sh_s[C_];

    const int st = blockIdx.x;
    const int n  = blockIdx.y;
    const int tid = threadIdx.x;
    const int w = tid >> 6;       // wave 0..7
    const int l = tid & 63;       // lane
    const int s0 = st * ST_;
    const size_t xbase = (size_t)n * C_ * TV_ + s0;

    // stage scale/shift/A (fixed: full grid-stride for the 441 A entries)
    if (tid < C_) { sc_s[tid] = sc_g[tid]; sh_s[tid] = sh_g[tid]; }
    for (int i = tid; i < V_ * V_; i += 512) A_s[i] = A_g[(size_t)n * V_ * V_ + i];

    // W fragments (A-operand): lane l holds W[16w+(l&15)][kk*32 + 8*(l>>4) + j]
    const int o_row = 16 * w + (l & 15);
    const int hi = l >> 4;
    const int coff0 = 8 * hi;
    bf16x8 wf[4];
    #pragma unroll
    for (int kk = 0; kk < 4; ++kk)
        wf[kk] = *(const bf16x8*)((const short*)w_bf + o_row * C_ + kk * 32 + coff0);

    // stage X_t[s][c] bf16, swizzle byte ^= (s&7)<<4. 4 c's x 4 s's per iteration.
    for (int idx = tid; idx < (C_ / 4) * (ST_ / 4); idx += 512) {
        int cg = idx / (ST_ / 4), q = idx - cg * (ST_ / 4);
        int c0 = cg * 4, sq = q * 4;
        f32x4 f[4];
        #pragma unroll
        for (int i = 0; i < 4; ++i)
            f[i] = *(const f32x4*)(x + xbase + (size_t)(c0 + i) * TV_ + sq);
        #pragma unroll
        for (int i = 0; i < 4; ++i) {
            int s = sq + i;
            s16x4 pk;
            #pragma unroll
            for (int j = 0; j < 4; ++j) pk[j] = f2bf(f[j][i]);
            int byte = (s * 256 + c0 * 2) ^ ((s & 7) << 4);
            *(s16x4*)(lds + byte) = pk;
        }
    }
    // zero pad rows s = 168..175
    if (tid < 256) {
        int s = ST_ + (tid >> 5);
        int c4 = (tid & 31) * 4;
        int byte = (s * 256 + c4 * 2) ^ ((s & 7) << 4);
        *(unsigned long long*)(lds + byte) = 0ull;
    }
    __syncthreads();

    // GEMM: 11 N-frags, K = 128 in 4 steps
    f32x4 acc[11];
    #pragma unroll
    for (int nf = 0; nf < 11; ++nf) acc[nf] = (f32x4){0.f, 0.f, 0.f, 0.f};
    #pragma unroll
    for (int kk = 0; kk < 4; ++kk) {
        #pragma unroll
        for (int nf = 0; nf < 11; ++nf) {
            int srow = 16 * nf + (l & 15);
            int byte = (srow * 256 + (kk * 32 + coff0) * 2) ^ ((srow & 7) << 4);
            bf16x8 b = *(const bf16x8*)(lds + byte);
            acc[nf] = __builtin_amdgcn_mfma_f32_16x16x32_bf16(wf[kk], b, acc[nf], 0, 0, 0);
        }
    }

    // epilogue in two 64-channel passes; xf kept fp32 in LDS
    const int obase = 16 * w + 4 * hi;          // global o base of this thread's 4 acc rows
    const int obase_local = obase & 63;
    float scr[4], shr[4];
    #pragma unroll
    for (int r = 0; r < 4; ++r) { scr[r] = sc_s[obase + r]; shr[r] = sh_s[obase + r]; }
    float* lds_f = (float*)lds;

    #pragma unroll
    for (int pass = 0; pass < 2; ++pass) {
        __syncthreads();   // previous buffer contents fully consumed
        if ((w >> 2) == pass) {
            #pragma unroll
            for (int nf = 0; nf < 11; ++nf) {
                int s = 16 * nf + (l & 15);
                if (s < ST_) {
                    #pragma unroll
                    for (int r = 0; r < 4; ++r) {
                        float vv = fmaxf(fmaf(acc[nf][r], scr[r], shr[r]), 0.f);
                        lds_f[(obase_local + r) * XF_PITCH_F + s] = vv;
                    }
                }
            }
        }
        __syncthreads();
        // A-transform + residual + store for o in [64*pass, 64*pass+64)
        for (int idx = tid; idx < 64 * ST_; idx += 512) {
            int o2 = idx / ST_, s = idx - o2 * ST_;
            int t = s / V_, v = s - t * V_;
            const float* xrow = lds_f + o2 * XF_PITCH_F + t * V_;
            float sum = 0.f;
            #pragma unroll
            for (int u = 0; u < V_; ++u) sum = fmaf(xrow[u], A_s[u * V_ + v], sum);
            size_t g = xbase + (size_t)(pass * 64 + o2) * TV_ + s;
            out[g] = sum + x[g];
        }
    }
}

extern "C" void kernel_launch(void* const* d_in, const int* in_sizes, int n_in,
                              void* d_out, int out_size, void* d_ws, size_t ws_size,
                              hipStream_t stream) {
    const float* x         = (const float*)d_in[0];
    const float* dyn_w     = (const float*)d_in[1];
    const float* dyn_b     = (const float*)d_in[2];
    const float* dyn_gamma = (const float*)d_in[3];
    const float* dyn_beta  = (const float*)d_in[4];
    const float* dyn_mean  = (const float*)d_in[5];
    const float* dyn_var   = (const float*)d_in[6];
    const float* ft_w      = (const float*)d_in[7];
    const float* ft_b      = (const float*)d_in[8];
    const float* ft_gamma  = (const float*)d_in[9];
    const float* ft_beta   = (const float*)d_in[10];
    const float* ft_mean   = (const float*)d_in[11];
    const float* ft_var    = (const float*)d_in[12];
    float* out = (float*)d_out;

    char* ws = (char*)d_ws;
    float* xm  = (float*)ws;                                   ws += (size_t)N_ * C_ * V_ * 4;
    float* A_g = (float*)ws;                                   ws += (size_t)N_ * V_ * V_ * 4;
    __hip_bfloat16* w_bf = (__hip_bfloat16*)ws;                ws += (size_t)C_ * C_ * 2;
    float* sc_g = (float*)ws;                                  ws += C_ * 4;
    float* sh_g = (float*)ws;                                  ws += C_ * 4;

    prep_kernel<<<64, 256, 0, stream>>>(ft_w, ft_b, ft_gamma, ft_beta, ft_mean, ft_var,
                                        w_bf, sc_g, sh_g);
    mean_kernel<<<N_ * C_, 256, 0, stream>>>(x, xm);
    hyper_kernel<<<N_, 64, 0, stream>>>(xm, dyn_w, dyn_b, dyn_gamma, dyn_beta,
                                        dyn_mean, dyn_var, A_g);
    main_kernel<<<dim3(32, 128), 512, 0, stream>>>(x, w_bf, sc_g, sh_g, A_g, out);
}

// Round 4
// 336.758 us; speedup vs baseline: 2.4817x; 1.2381x over previous
//
#include <hip/hip_runtime.h>
#include <hip/hip_bf16.h>
#include <math.h>

#define EPS 1e-5f

static constexpr int N_ = 128, C_ = 128, T_ = 256, V_ = 21, E_ = 8, M_ = 13;
static constexpr int TV_ = T_ * V_;   // 5376
static constexpr int NT_ = 8;         // t's per main block
static constexpr int ST_ = NT_ * V_;  // 168 s-columns per block
static constexpr int XF_PITCH = 48;   // bytes per xf row (24 bf16 slots, 21 used)

typedef short bf16x8 __attribute__((ext_vector_type(8)));
typedef short s16x4  __attribute__((ext_vector_type(4)));
typedef float f32x4  __attribute__((ext_vector_type(4)));

__device__ inline short f2bf(float v) {
    __hip_bfloat16 b = __float2bfloat16(v);
    return *reinterpret_cast<short*>(&b);
}

// ---------------- Kernel P: fold BN + convert W to bf16 ----------------
__global__ __launch_bounds__(256) void prep_kernel(
    const float* __restrict__ ft_w, const float* __restrict__ ft_b,
    const float* __restrict__ ft_gamma, const float* __restrict__ ft_beta,
    const float* __restrict__ ft_mean, const float* __restrict__ ft_var,
    __hip_bfloat16* __restrict__ w_bf, float* __restrict__ sc_g, float* __restrict__ sh_g)
{
    int tid = blockIdx.x * 256 + threadIdx.x;
    if (tid < C_ * C_) w_bf[tid] = __float2bfloat16(ft_w[tid]);
    if (tid < C_) {
        float sc = ft_gamma[tid] * rsqrtf(ft_var[tid] + EPS);
        sc_g[tid] = sc;
        sh_g[tid] = (ft_b[tid] - ft_mean[tid]) * sc + ft_beta[tid];
    }
}

// ---------------- Kernel A: mean over T ----------------
__global__ __launch_bounds__(256) void mean_kernel(const float* __restrict__ x,
                                                   float* __restrict__ xm) {
    __shared__ float slab[TV_];
    __shared__ float partial[V_ * 8];
    const int nc = blockIdx.x;
    const int tid = threadIdx.x;
    const float4* src4 = (const float4*)(x + (size_t)nc * TV_);
    float4* slab4 = (float4*)slab;
    #pragma unroll
    for (int it = 0; it < 6; ++it) {
        int idx = it * 256 + tid;
        if (idx < TV_ / 4) slab4[idx] = src4[idx];
    }
    __syncthreads();
    if (tid < V_ * 8) {
        int v = tid >> 3, g = tid & 7;
        float s = 0.f;
        #pragma unroll
        for (int tt = 0; tt < 32; ++tt) s += slab[(g * 32 + tt) * V_ + v];
        partial[v * 8 + g] = s;
    }
    __syncthreads();
    if (tid < V_) {
        float s = 0.f;
        #pragma unroll
        for (int g = 0; g < 8; ++g) s += partial[tid * 8 + g];
        xm[(size_t)nc * V_ + tid] = s * (1.0f / T_);
    }
}

// ---------------- Kernel B: H_dyn + A = H^T H (bf16, 32x32 zero-padded) ----------------
__global__ __launch_bounds__(64) void hyper_kernel(
    const float* __restrict__ xm, const float* __restrict__ dyn_w,
    const float* __restrict__ dyn_b,
    const float* __restrict__ dyn_gamma, const float* __restrict__ dyn_beta,
    const float* __restrict__ dyn_mean, const float* __restrict__ dyn_var,
    __hip_bfloat16* __restrict__ A_bf)               // (N,32,32)
{
    __shared__ float xs[C_ * V_];
    __shared__ float Hs[M_ * V_];
    const int n = blockIdx.x;
    const int l = threadIdx.x;
    const float* src = xm + (size_t)n * C_ * V_;
    for (int idx = l; idx < C_ * V_; idx += 64) xs[idx] = src[idx];
    __syncthreads();
    for (int idx = l; idx < E_ * V_; idx += 64) {
        int e = idx / V_, v = idx - e * V_;
        float acc = 0.f;
        for (int c = 0; c < C_; ++c) acc = fmaf(xs[c * V_ + v], dyn_w[e * C_ + c], acc);
        acc += dyn_b[e];
        float scale = dyn_gamma[e] * rsqrtf(dyn_var[e] + EPS);
        acc = (acc - dyn_mean[e]) * scale + dyn_beta[e];
        Hs[idx] = fmaxf(acc, 0.f);
    }
    __syncthreads();
    if (l < E_) {
        float row[V_];
        float mx = -1e30f;
        #pragma unroll
        for (int v = 0; v < V_; ++v) { row[v] = Hs[l * V_ + v]; mx = fmaxf(mx, row[v]); }
        float s = 0.f;
        #pragma unroll
        for (int v = 0; v < V_; ++v) { row[v] = __expf(row[v] - mx); s += row[v]; }
        float inv = 1.0f / s;
        #pragma unroll
        for (int v = 0; v < V_; ++v) Hs[l * V_ + v] = row[v] * inv;
    } else if (l < M_) {
        int i = l - E_;
        #pragma unroll
        for (int v = 0; v < V_; ++v)
            Hs[l * V_ + v] = (v >= 1 + 4 * i && v < 5 + 4 * i) ? 1.0f : 0.0f;
    }
    __syncthreads();
    // A (symmetric) zero-padded to 32x32, bf16
    for (int idx = l; idx < 32 * 32; idx += 64) {
        int u = idx >> 5, v = idx & 31;
        float s = 0.f;
        if (u < V_ && v < V_) {
            #pragma unroll
            for (int m = 0; m < M_; ++m) s = fmaf(Hs[m * V_ + u], Hs[m * V_ + v], s);
        }
        A_bf[(size_t)n * 1024 + idx] = __float2bfloat16(s);
    }
}

// ---------------- Kernel C: MFMA GEMM + BN/ReLU + MFMA A-transform + residual ----------------
// grid (32 s-tiles, 128 n), 512 threads = 8 waves. Wave w owns o in [16w, 16w+16).
__global__ __launch_bounds__(512) void main_kernel(
    const float* __restrict__ x, const __hip_bfloat16* __restrict__ w_bf,
    const float* __restrict__ sc_g, const float* __restrict__ sh_g,
    const __hip_bfloat16* __restrict__ A_bf, float* __restrict__ out)
{
    // phase 1: X_t[s=176][c=128] bf16 swizzled (45056 B)
    // phase 2: xf[(o*8+t)=1024][24 bf16] pitch 48 B (49152 B + 128 pad)
    __shared__ __align__(16) char lds[49280];
    __shared__ float sc_s[C_], sh_s[C_];

    const int st = blockIdx.x;
    const int n  = blockIdx.y;
    const int tid = threadIdx.x;
    const int w = tid >> 6;       // wave 0..7
    const int l = tid & 63;       // lane
    const int hi = l >> 4;        // 0..3
    const int lo = l & 15;
    const int s0 = st * ST_;
    const size_t xbase = (size_t)n * C_ * TV_ + s0;

    if (tid < C_) { sc_s[tid] = sc_g[tid]; sh_s[tid] = sh_g[tid]; }

    // W fragments (GEMM1 A-operand): lane holds W[16w+lo][kk*32 + 8*hi + j]
    const int o_row = 16 * w + lo;
    bf16x8 wf[4];
    #pragma unroll
    for (int kk = 0; kk < 4; ++kk)
        wf[kk] = *(const bf16x8*)((const short*)w_bf + o_row * C_ + kk * 32 + 8 * hi);

    // GEMM2 B-fragments from global A_bf (issued early; tiny, L2-hot)
    const short* Abf_n = (const short*)A_bf + (size_t)n * 1024;
    const bf16x8 bA0 = *(const bf16x8*)(Abf_n + lo * 32 + 8 * hi);         // cols v=0..15
    const bf16x8 bA1 = *(const bf16x8*)(Abf_n + (16 + lo) * 32 + 8 * hi);  // cols v=16..31

    // stage X_t[s][c] bf16, swizzle byte ^= (s&7)<<4. 4 c's x 4 s's per iter.
    for (int idx = tid; idx < (C_ / 4) * (ST_ / 4); idx += 512) {
        int cg = idx / (ST_ / 4), q = idx - cg * (ST_ / 4);
        int c0 = cg * 4, sq = q * 4;
        f32x4 f[4];
        #pragma unroll
        for (int i = 0; i < 4; ++i)
            f[i] = *(const f32x4*)(x + xbase + (size_t)(c0 + i) * TV_ + sq);
        #pragma unroll
        for (int i = 0; i < 4; ++i) {
            int s = sq + i;
            s16x4 pk;
            #pragma unroll
            for (int j = 0; j < 4; ++j) pk[j] = f2bf(f[j][i]);
            int byte = (s * 256 + c0 * 2) ^ ((s & 7) << 4);
            *(s16x4*)(lds + byte) = pk;
        }
    }
    // zero pad rows s = 168..175 of the staging layout
    if (tid < 256) {
        int s = ST_ + (tid >> 5);
        int c4 = (tid & 31) * 4;
        int byte = (s * 256 + c4 * 2) ^ ((s & 7) << 4);
        *(unsigned long long*)(lds + byte) = 0ull;
    }
    __syncthreads();

    // GEMM1: 11 N-frags, K = 128 in 4 steps
    f32x4 acc[11];
    #pragma unroll
    for (int nf = 0; nf < 11; ++nf) acc[nf] = (f32x4){0.f, 0.f, 0.f, 0.f};
    #pragma unroll
    for (int kk = 0; kk < 4; ++kk) {
        #pragma unroll
        for (int nf = 0; nf < 11; ++nf) {
            int srow = 16 * nf + lo;
            int byte = (srow * 256 + (kk * 32 + 8 * hi) * 2) ^ ((srow & 7) << 4);
            bf16x8 b = *(const bf16x8*)(lds + byte);
            acc[nf] = __builtin_amdgcn_mfma_f32_16x16x32_bf16(wf[kk], b, acc[nf], 0, 0, 0);
        }
    }
    __syncthreads();   // staging reads complete; buffer becomes xf

    // BN + ReLU -> xf bf16 at row (o*8+t), col u; pitch 48 B
    const int obase = 16 * w + 4 * hi;
    float scr[4], shr[4];
    #pragma unroll
    for (int r = 0; r < 4; ++r) { scr[r] = sc_s[obase + r]; shr[r] = sh_s[obase + r]; }
    #pragma unroll
    for (int nf = 0; nf < 11; ++nf) {
        int s = 16 * nf + lo;
        if (s < ST_) {
            int t = s / V_, u = s - t * V_;
            #pragma unroll
            for (int r = 0; r < 4; ++r) {
                float vv = fmaxf(fmaf(acc[nf][r], scr[r], shr[r]), 0.f);
                *(short*)(lds + ((obase + r) * 8 + t) * XF_PITCH + u * 2) = f2bf(vv);
            }
        }
    }
    // zero the u=21..23 pad of every row (avoid NaN garbage; k>=21 hits zero B anyway)
    for (int row = tid; row < 1024; row += 512) {
        *(short*)(lds + row * XF_PITCH + 42) = 0;
        *(int*)(lds + row * XF_PITCH + 44) = 0;
    }
    if (tid < 4) *(int*)(lds + 49152 + tid * 4) = 0;   // row-1023 k=24..31 overspill
    __syncthreads();

    // GEMM2: Xr = xf (1024x32) * A (32x32), wave w owns M-frags 8w..8w+7
    bf16x8 xfr[8];
    #pragma unroll
    for (int i = 0; i < 8; ++i) {
        int row = 16 * (8 * w + i) + lo;
        xfr[i] = *(const bf16x8*)(lds + row * XF_PITCH + 16 * hi);
    }
    #pragma unroll
    for (int i = 0; i < 8; ++i) {
        f32x4 d0 = (f32x4){0.f, 0.f, 0.f, 0.f};
        f32x4 d1 = (f32x4){0.f, 0.f, 0.f, 0.f};
        d0 = __builtin_amdgcn_mfma_f32_16x16x32_bf16(xfr[i], bA0, d0, 0, 0, 0);
        d1 = __builtin_amdgcn_mfma_f32_16x16x32_bf16(xfr[i], bA1, d1, 0, 0, 0);
        int row0 = 16 * (8 * w + i) + 4 * hi;
        #pragma unroll
        for (int r = 0; r < 4; ++r) {
            int row = row0 + r;
            int o = row >> 3, t = row & 7;
            size_t g = xbase + (size_t)o * TV_ + t * V_;
            out[g + lo] = d0[r] + x[g + lo];
            if (lo < V_ - 16) out[g + 16 + lo] = d1[r] + x[g + 16 + lo];
        }
    }
}

extern "C" void kernel_launch(void* const* d_in, const int* in_sizes, int n_in,
                              void* d_out, int out_size, void* d_ws, size_t ws_size,
                              hipStream_t stream) {
    const float* x         = (const float*)d_in[0];
    const float* dyn_w     = (const float*)d_in[1];
    const float* dyn_b     = (const float*)d_in[2];
    const float* dyn_gamma = (const float*)d_in[3];
    const float* dyn_beta  = (const float*)d_in[4];
    const float* dyn_mean  = (const float*)d_in[5];
    const float* dyn_var   = (const float*)d_in[6];
    const float* ft_w      = (const float*)d_in[7];
    const float* ft_b      = (const float*)d_in[8];
    const float* ft_gamma  = (const float*)d_in[9];
    const float* ft_beta   = (const float*)d_in[10];
    const float* ft_mean   = (const float*)d_in[11];
    const float* ft_var    = (const float*)d_in[12];
    float* out = (float*)d_out;

    char* ws = (char*)d_ws;
    float* xm  = (float*)ws;                                   ws += (size_t)N_ * C_ * V_ * 4;
    __hip_bfloat16* A_bf = (__hip_bfloat16*)ws;                ws += (size_t)N_ * 1024 * 2;
    __hip_bfloat16* w_bf = (__hip_bfloat16*)ws;                ws += (size_t)C_ * C_ * 2;
    float* sc_g = (float*)ws;                                  ws += C_ * 4;
    float* sh_g = (float*)ws;                                  ws += C_ * 4;

    prep_kernel<<<64, 256, 0, stream>>>(ft_w, ft_b, ft_gamma, ft_beta, ft_mean, ft_var,
                                        w_bf, sc_g, sh_g);
    mean_kernel<<<N_ * C_, 256, 0, stream>>>(x, xm);
    hyper_kernel<<<N_, 64, 0, stream>>>(xm, dyn_w, dyn_b, dyn_gamma, dyn_beta,
                                        dyn_mean, dyn_var, A_bf);
    main_kernel<<<dim3(32, 128), 512, 0, stream>>>(x, w_bf, sc_g, sh_g, A_bf, out);
}